// Round 1
// baseline (689.599 us; speedup 1.0000x reference)
//
#include <hip/hip_runtime.h>
#include <hip/hip_bf16.h>

#define NH 16
#define HS 64
#define CE 1024
#define BB 4
#define TT 2048

typedef __bf16 bf16;
typedef __bf16 v8bf __attribute__((ext_vector_type(8)));
typedef __bf16 v4bf __attribute__((ext_vector_type(4)));
typedef __bf16 v2bf __attribute__((ext_vector_type(2)));
typedef float v4f __attribute__((ext_vector_type(4)));

// ---------------- cast x (fp32 -> bf16), 8 elems/thread ----------------
__global__ __launch_bounds__(256) void cast_x_kernel(const float* __restrict__ x,
                                                     bf16* __restrict__ xb) {
    int idx = (blockIdx.x * 256 + threadIdx.x) * 8;
    const float4* xp = (const float4*)(x + idx);
    float4 a = xp[0], b = xp[1];
    v8bf o;
    o[0] = (bf16)a.x; o[1] = (bf16)a.y; o[2] = (bf16)a.z; o[3] = (bf16)a.w;
    o[4] = (bf16)b.x; o[5] = (bf16)b.y; o[6] = (bf16)b.z; o[7] = (bf16)b.w;
    *(v8bf*)(xb + idx) = o;
}

// ---------------- transpose + cast weight: W (K x N fp32) -> Wt (N x K bf16) ----------------
__global__ __launch_bounds__(256) void transpose_w_kernel(const float* __restrict__ W,
                                                          bf16* __restrict__ Wt) {
    __shared__ bf16 tile[64][66];
    int k0 = blockIdx.x * 64;
    int n0 = blockIdx.y * 64;
    int tx = threadIdx.x & 63;
    int ty = threadIdx.x >> 6;  // 0..3
    for (int s = 0; s < 16; s++) {
        int r = s * 4 + ty;
        tile[r][tx] = (bf16)W[(size_t)(k0 + r) * CE + n0 + tx];
    }
    __syncthreads();
    for (int s = 0; s < 16; s++) {
        int r = s * 4 + ty;
        Wt[(size_t)(n0 + r) * CE + k0 + tx] = tile[tx][r];
    }
}

// ---------------- GEMM: C(8192x1024) = A(8192x1024 bf16) * Bt(1024x1024 bf16, N-major)^T --------
// MODE 0: out bf16 [B][H][T][HS]      (Q or K, pre-RoPE)
// MODE 1: out fp32 [M][N] + bias      (final projection -> d_out)
// MODE 2: out bf16 [B][H][HS][T]      (V transposed for attention B-operand)
template <int MODE>
__global__ __launch_bounds__(256) void gemm_bt(const bf16* __restrict__ A,
                                               const bf16* __restrict__ Bt,
                                               void* __restrict__ outp,
                                               const float* __restrict__ bias) {
    __shared__ __align__(16) bf16 As[128 * 32];
    __shared__ __align__(16) bf16 Bs[128 * 32];
    const int tid = threadIdx.x;
    const int lane = tid & 63, wave = tid >> 6;
    const int lane15 = lane & 15, quad = lane >> 4;
    const int wr = wave >> 1, wc = wave & 1;
    const int m0 = blockIdx.y * 128;
    const int n0 = blockIdx.x * 128;

    v4f acc[4][4] = {};

    const int cm = tid >> 2;          // 0..63 (row within 64-row half tile)
    const int ck = (tid & 3) * 8;     // k chunk offset
    const bf16* Ag = A + (size_t)(m0 + cm) * CE + ck;
    const bf16* Bg = Bt + (size_t)(n0 + cm) * CE + ck;

    for (int k0 = 0; k0 < CE; k0 += 32) {
        v8bf a0 = *(const v8bf*)(Ag + k0);
        v8bf a1 = *(const v8bf*)(Ag + k0 + (size_t)64 * CE);
        v8bf b0 = *(const v8bf*)(Bg + k0);
        v8bf b1 = *(const v8bf*)(Bg + k0 + (size_t)64 * CE);
        __syncthreads();  // protect LDS from previous iteration's readers
        *(v8bf*)(&As[cm * 32 + ck]) = a0;
        *(v8bf*)(&As[(cm + 64) * 32 + ck]) = a1;
        *(v8bf*)(&Bs[cm * 32 + ck]) = b0;
        *(v8bf*)(&Bs[(cm + 64) * 32 + ck]) = b1;
        __syncthreads();
        v8bf af[4], bfr[4];
        for (int i = 0; i < 4; i++)
            af[i] = *(const v8bf*)(&As[(wr * 64 + i * 16 + lane15) * 32 + quad * 8]);
        for (int j = 0; j < 4; j++)
            bfr[j] = *(const v8bf*)(&Bs[(wc * 64 + j * 16 + lane15) * 32 + quad * 8]);
        for (int i = 0; i < 4; i++)
            for (int j = 0; j < 4; j++)
                acc[i][j] = __builtin_amdgcn_mfma_f32_16x16x32_bf16(af[i], bfr[j], acc[i][j], 0, 0, 0);
    }

    for (int i = 0; i < 4; i++) {
        for (int j = 0; j < 4; j++) {
            int gmb = m0 + wr * 64 + i * 16 + quad * 4;
            int gn = n0 + wc * 64 + j * 16 + lane15;
            if (MODE == 1) {
                float bb = bias[gn];
                float* out = (float*)outp;
                for (int r = 0; r < 4; r++)
                    out[(size_t)(gmb + r) * CE + gn] = acc[i][j][r] + bb;
            } else if (MODE == 0) {
                bf16* out = (bf16*)outp;
                int h = gn >> 6, d = gn & 63;
                for (int r = 0; r < 4; r++) {
                    int gm = gmb + r;
                    int b = gm >> 11, t = gm & 2047;
                    out[(((size_t)(b * NH + h)) * TT + t) * HS + d] = (bf16)acc[i][j][r];
                }
            } else {  // MODE 2: Vt [B][H][HS][T]
                bf16* out = (bf16*)outp;
                int h = gn >> 6, d = gn & 63;
                int b = gmb >> 11, t = gmb & 2047;
                v4bf pack;
                for (int r = 0; r < 4; r++) pack[r] = (bf16)acc[i][j][r];
                *(v4bf*)(&out[(((size_t)(b * NH + h)) * HS + d) * TT + t]) = pack;
            }
        }
    }
}

// ---------------- RoPE in-place on Q/K bf16 [B][H][T][HS] ----------------
__global__ __launch_bounds__(256) void rope_kernel(bf16* __restrict__ Qb, bf16* __restrict__ Kb) {
    unsigned idx = blockIdx.x * 256 + threadIdx.x;  // 0 .. 4M-1 (pairs)
    bf16* buf = blockIdx.y ? Kb : Qb;
    int i = idx & 31;
    int t = (idx >> 5) & 2047;
    float inv = exp2f(-0.41524101186092034f * (float)i);  // 10000^(-i/32)
    float ang = (float)t * inv;
    float s, c;
    sincosf(ang, &s, &c);
    bf16* p = buf + (size_t)idx * 2;
    v2bf v = *(v2bf*)p;
    float x0 = (float)v[0], x1 = (float)v[1];
    v2bf o;
    o[0] = (bf16)(x0 * c - x1 * s);
    o[1] = (bf16)(x0 * s + x1 * c);
    *(v2bf*)p = o;
}

// ---------------- flash attention: 1 wave = 16 query rows ----------------
__global__ __launch_bounds__(256) void attn_kernel(const bf16* __restrict__ Qb,
                                                   const bf16* __restrict__ Kb,
                                                   const bf16* __restrict__ Vt,
                                                   bf16* __restrict__ Ob) {
    __shared__ __align__(16) bf16 Pl[4][16 * 32];
    const int tid = threadIdx.x, lane = tid & 63, wave = tid >> 6;
    const int lane15 = lane & 15, quad = lane >> 4;
    const int tile = blockIdx.x * 4 + wave;  // 0..8191
    const int bh = tile >> 7, qt = tile & 127;
    const int q0 = qt * 16;
    const bf16* Qp = Qb + (size_t)bh * TT * HS;
    const bf16* Kp = Kb + (size_t)bh * TT * HS;
    const bf16* Vp = Vt + (size_t)bh * HS * TT;

    v8bf qa0 = *(const v8bf*)(Qp + (q0 + lane15) * HS + quad * 8);
    v8bf qa1 = *(const v8bf*)(Qp + (q0 + lane15) * HS + 32 + quad * 8);

    v4f o[4] = {};
    float m_i[4], l_i[4];
    for (int r = 0; r < 4; r++) { m_i[r] = -1e30f; l_i[r] = 0.f; }

    const int kv_end = q0 + 16;
    for (int kv0 = 0; kv0 < kv_end; kv0 += 32) {
        v4f s0 = {}, s1 = {};
        {
            int kr = kv0 + lane15;
            v8bf kb0 = *(const v8bf*)(Kp + kr * HS + quad * 8);
            v8bf kb1 = *(const v8bf*)(Kp + kr * HS + 32 + quad * 8);
            s0 = __builtin_amdgcn_mfma_f32_16x16x32_bf16(qa0, kb0, s0, 0, 0, 0);
            s0 = __builtin_amdgcn_mfma_f32_16x16x32_bf16(qa1, kb1, s0, 0, 0, 0);
        }
        {
            int kr = kv0 + 16 + lane15;
            v8bf kb0 = *(const v8bf*)(Kp + kr * HS + quad * 8);
            v8bf kb1 = *(const v8bf*)(Kp + kr * HS + 32 + quad * 8);
            s1 = __builtin_amdgcn_mfma_f32_16x16x32_bf16(qa0, kb0, s1, 0, 0, 0);
            s1 = __builtin_amdgcn_mfma_f32_16x16x32_bf16(qa1, kb1, s1, 0, 0, 0);
        }
        float alpha[4];
        for (int r = 0; r < 4; r++) {
            int row = q0 + quad * 4 + r;
            float ve0 = (kv0 + lane15 <= row) ? s0[r] * 0.125f : -1e30f;
            float ve1 = (kv0 + 16 + lane15 <= row) ? s1[r] * 0.125f : -1e30f;
            float mx = fmaxf(ve0, ve1);
            for (int off = 1; off < 16; off <<= 1)
                mx = fmaxf(mx, __shfl_xor(mx, off));
            float mn = fmaxf(m_i[r], mx);
            alpha[r] = __expf(m_i[r] - mn);
            m_i[r] = mn;
            float p0 = __expf(ve0 - mn);
            float p1 = __expf(ve1 - mn);
            float rs = p0 + p1;
            for (int off = 1; off < 16; off <<= 1)
                rs += __shfl_xor(rs, off);
            l_i[r] = l_i[r] * alpha[r] + rs;
            Pl[wave][(quad * 4 + r) * 32 + lane15] = (bf16)p0;
            Pl[wave][(quad * 4 + r) * 32 + 16 + lane15] = (bf16)p1;
        }
        for (int j = 0; j < 4; j++)
            for (int r = 0; r < 4; r++)
                o[j][r] *= alpha[r];
        v8bf pa = *(const v8bf*)(&Pl[wave][lane15 * 32 + quad * 8]);
        for (int j = 0; j < 4; j++) {
            v8bf vb = *(const v8bf*)(Vp + (size_t)(j * 16 + lane15) * TT + kv0 + quad * 8);
            o[j] = __builtin_amdgcn_mfma_f32_16x16x32_bf16(pa, vb, o[j], 0, 0, 0);
        }
    }
    const int b = bh >> 4, h = bh & 15;
    float inv_l[4];
    for (int r = 0; r < 4; r++) inv_l[r] = 1.f / l_i[r];
    for (int j = 0; j < 4; j++)
        for (int r = 0; r < 4; r++) {
            int t = q0 + quad * 4 + r;
            Ob[((size_t)(b * TT + t)) * CE + h * HS + j * 16 + lane15] = (bf16)(o[j][r] * inv_l[r]);
        }
}

extern "C" void kernel_launch(void* const* d_in, const int* in_sizes, int n_in,
                              void* d_out, int out_size, void* d_ws, size_t ws_size,
                              hipStream_t stream) {
    const float* x  = (const float*)d_in[0];
    const float* Wq = (const float*)d_in[1];
    const float* Wk = (const float*)d_in[2];
    const float* Wv = (const float*)d_in[3];
    const float* Wp = (const float*)d_in[4];
    const float* bp = (const float*)d_in[5];
    char* ws = (char*)d_ws;
    const size_t MB = 1024 * 1024;
    bf16* Xb  = (bf16*)(ws);
    bf16* WqT = (bf16*)(ws + 16 * MB);
    bf16* WkT = (bf16*)(ws + 18 * MB);
    bf16* WvT = (bf16*)(ws + 20 * MB);
    bf16* WpT = (bf16*)(ws + 22 * MB);
    bf16* Qb  = (bf16*)(ws + 24 * MB);
    bf16* Kb  = (bf16*)(ws + 40 * MB);
    bf16* Vt  = (bf16*)(ws + 56 * MB);
    bf16* Ob  = (bf16*)(ws + 72 * MB);

    cast_x_kernel<<<dim3(4096), dim3(256), 0, stream>>>(x, Xb);
    transpose_w_kernel<<<dim3(16, 16), dim3(256), 0, stream>>>(Wq, WqT);
    transpose_w_kernel<<<dim3(16, 16), dim3(256), 0, stream>>>(Wk, WkT);
    transpose_w_kernel<<<dim3(16, 16), dim3(256), 0, stream>>>(Wv, WvT);
    transpose_w_kernel<<<dim3(16, 16), dim3(256), 0, stream>>>(Wp, WpT);

    dim3 gg(8, 64);
    gemm_bt<0><<<gg, dim3(256), 0, stream>>>(Xb, WqT, (void*)Qb, nullptr);
    gemm_bt<0><<<gg, dim3(256), 0, stream>>>(Xb, WkT, (void*)Kb, nullptr);
    gemm_bt<2><<<gg, dim3(256), 0, stream>>>(Xb, WvT, (void*)Vt, nullptr);

    rope_kernel<<<dim3(16384, 2), dim3(256), 0, stream>>>(Qb, Kb);

    attn_kernel<<<dim3(2048), dim3(256), 0, stream>>>(Qb, Kb, Vt, Ob);

    gemm_bt<1><<<gg, dim3(256), 0, stream>>>(Ob, WpT, d_out, bp);
}

// Round 2
// 309.961 us; speedup vs baseline: 2.2248x; 2.2248x over previous
//
#include <hip/hip_runtime.h>
#include <hip/hip_bf16.h>

#define NH 16
#define HS 64
#define CE 1024
#define BB 4
#define TT 2048

typedef __bf16 bf16;
typedef __bf16 v8bf __attribute__((ext_vector_type(8)));
typedef __bf16 v4bf __attribute__((ext_vector_type(4)));
typedef __bf16 v2bf __attribute__((ext_vector_type(2)));
typedef float v4f __attribute__((ext_vector_type(4)));
typedef float v16f __attribute__((ext_vector_type(16)));

#define GLD16(gp, lp)                                                              \
    __builtin_amdgcn_global_load_lds((const __attribute__((address_space(1))) void*)(gp), \
                                     (__attribute__((address_space(3))) void*)(lp), 16, 0, 0)

// ---------------- cast x (fp32 -> bf16), 8 elems/thread ----------------
__global__ __launch_bounds__(256) void cast_x_kernel(const float* __restrict__ x,
                                                     bf16* __restrict__ xb) {
    int idx = (blockIdx.x * 256 + threadIdx.x) * 8;
    const float4* xp = (const float4*)(x + idx);
    float4 a = xp[0], b = xp[1];
    v8bf o;
    o[0] = (bf16)a.x; o[1] = (bf16)a.y; o[2] = (bf16)a.z; o[3] = (bf16)a.w;
    o[4] = (bf16)b.x; o[5] = (bf16)b.y; o[6] = (bf16)b.z; o[7] = (bf16)b.w;
    *(v8bf*)(xb + idx) = o;
}

// ---------------- transpose + cast weight: W (K x N fp32) -> Wt (N x K bf16) ----------------
__global__ __launch_bounds__(256) void transpose_w_kernel(const float* __restrict__ W,
                                                          bf16* __restrict__ Wt) {
    __shared__ bf16 tile[64][66];
    int k0 = blockIdx.x * 64;
    int n0 = blockIdx.y * 64;
    int tx = threadIdx.x & 63;
    int ty = threadIdx.x >> 6;  // 0..3
    for (int s = 0; s < 16; s++) {
        int r = s * 4 + ty;
        tile[r][tx] = (bf16)W[(size_t)(k0 + r) * CE + n0 + tx];
    }
    __syncthreads();
    for (int s = 0; s < 16; s++) {
        int r = s * 4 + ty;
        Wt[(size_t)(n0 + r) * CE + k0 + tx] = tile[tx][r];
    }
}

// ---------------- GEMM: C(8192x1024) = A(8192x1024 bf16) * Bt(1024x1024 bf16, N-major)^T --------
// MODE 0: out bf16 [B][H][T][HS]      (Q or K, pre-RoPE)
// MODE 1: out fp32 [M][N] + bias      (final projection -> d_out)
// MODE 2: out bf16 [B][H][HS][T]      (V transposed for attention A-operand)
template <int MODE>
__global__ __launch_bounds__(256) void gemm_bt(const bf16* __restrict__ A,
                                               const bf16* __restrict__ Bt,
                                               void* __restrict__ outp,
                                               const float* __restrict__ bias) {
    __shared__ __align__(16) bf16 As[128 * 32];
    __shared__ __align__(16) bf16 Bs[128 * 32];
    const int tid = threadIdx.x;
    const int lane = tid & 63, wave = tid >> 6;
    const int lane15 = lane & 15, quad = lane >> 4;
    const int wr = wave >> 1, wc = wave & 1;
    const int m0 = blockIdx.y * 128;
    const int n0 = blockIdx.x * 128;

    v4f acc[4][4] = {};

    const int cm = tid >> 2;          // 0..63 (row within 64-row half tile)
    const int ck = (tid & 3) * 8;     // k chunk offset
    const bf16* Ag = A + (size_t)(m0 + cm) * CE + ck;
    const bf16* Bg = Bt + (size_t)(n0 + cm) * CE + ck;
    // global_load_lds dest = wave-uniform base + lane*16B; layout As[cm*32+ck] == byte tid*16
    bf16* aDst0 = &As[wave * 512];
    bf16* aDst1 = &As[2048 + wave * 512];
    bf16* bDst0 = &Bs[wave * 512];
    bf16* bDst1 = &Bs[2048 + wave * 512];

    for (int k0 = 0; k0 < CE; k0 += 32) {
        __syncthreads();  // previous iteration's readers done
        GLD16(Ag + k0, aDst0);
        GLD16(Ag + k0 + (size_t)64 * CE, aDst1);
        GLD16(Bg + k0, bDst0);
        GLD16(Bg + k0 + (size_t)64 * CE, bDst1);
        __syncthreads();  // vmcnt(0) drain + barrier
        v8bf af[4], bfr[4];
        for (int i = 0; i < 4; i++)
            af[i] = *(const v8bf*)(&As[(wr * 64 + i * 16 + lane15) * 32 + quad * 8]);
        for (int j = 0; j < 4; j++)
            bfr[j] = *(const v8bf*)(&Bs[(wc * 64 + j * 16 + lane15) * 32 + quad * 8]);
        for (int i = 0; i < 4; i++)
            for (int j = 0; j < 4; j++)
                acc[i][j] = __builtin_amdgcn_mfma_f32_16x16x32_bf16(af[i], bfr[j], acc[i][j], 0, 0, 0);
    }

    for (int i = 0; i < 4; i++) {
        for (int j = 0; j < 4; j++) {
            int gmb = m0 + wr * 64 + i * 16 + quad * 4;
            int gn = n0 + wc * 64 + j * 16 + lane15;
            if (MODE == 1) {
                float bb = bias[gn];
                float* out = (float*)outp;
                for (int r = 0; r < 4; r++)
                    out[(size_t)(gmb + r) * CE + gn] = acc[i][j][r] + bb;
            } else if (MODE == 0) {
                bf16* out = (bf16*)outp;
                int h = gn >> 6, d = gn & 63;
                for (int r = 0; r < 4; r++) {
                    int gm = gmb + r;
                    int b = gm >> 11, t = gm & 2047;
                    out[(((size_t)(b * NH + h)) * TT + t) * HS + d] = (bf16)acc[i][j][r];
                }
            } else {  // MODE 2: Vt [B][H][HS][T]
                bf16* out = (bf16*)outp;
                int h = gn >> 6, d = gn & 63;
                int b = gmb >> 11, t = gmb & 2047;
                v4bf pack;
                for (int r = 0; r < 4; r++) pack[r] = (bf16)acc[i][j][r];
                *(v4bf*)(&out[(((size_t)(b * NH + h)) * HS + d) * TT + t]) = pack;
            }
        }
    }
}

// ---------------- RoPE in-place on Q/K bf16 [B][H][T][HS] ----------------
__global__ __launch_bounds__(256) void rope_kernel(bf16* __restrict__ Qb, bf16* __restrict__ Kb) {
    unsigned idx = blockIdx.x * 256 + threadIdx.x;  // 0 .. 4M-1 (pairs)
    bf16* buf = blockIdx.y ? Kb : Qb;
    int i = idx & 31;
    int t = (idx >> 5) & 2047;
    float inv = exp2f(-0.41524101186092034f * (float)i);  // 10000^(-i/32)
    float ang = (float)t * inv;
    float s, c;
    sincosf(ang, &s, &c);
    bf16* p = buf + (size_t)idx * 2;
    v2bf v = *(v2bf*)p;
    float x0 = (float)v[0], x1 = (float)v[1];
    v2bf o;
    o[0] = (bf16)(x0 * c - x1 * s);
    o[1] = (bf16)(x0 * s + x1 * c);
    *(v2bf*)p = o;
}

// ---------------- flash attention v2: 1 wave = 32 q rows, S^T layout ----------------
// Block = 4 waves = 128 q rows of one (b,h). K/V tiles (32 kv) staged in LDS, shared.
// S^T = K·Q^T via mfma_32x32x16: C-layout col=lane&31=q, row=(reg&3)+8*(reg>>2)+4*(lane>>5)=kv.
// Each lane owns ONE q: softmax state (m,l) scalar per lane; reduction = in-reg tree + 1 shfl_xor(32).
// O^T = V^T·P^T accumulated in C-layout (d rows, q cols); P^T fragments built by one 8B
// shfl_xor(32) exchange per k-half (no LDS round-trip).
__global__ __launch_bounds__(256, 4) void attn_kernel(const bf16* __restrict__ Qb,
                                                      const bf16* __restrict__ Kb,
                                                      const bf16* __restrict__ Vt,
                                                      bf16* __restrict__ Ob) {
    __shared__ __align__(16) bf16 Ks[32 * 64];  // [kv][d], chunk-swizzled
    __shared__ __align__(16) bf16 Vs[64 * 32];  // [d][kv], chunk-swizzled
    const int tid = threadIdx.x, lane = tid & 63, wave = tid >> 6;
    const int lane31 = lane & 31, h = lane >> 5;
    const int qb = 15 - (int)(blockIdx.x >> 6);  // heavy blocks first
    const int bh = blockIdx.x & 63;
    const int q0 = qb * 128 + wave * 32;
    const bf16* Qp = Qb + (size_t)bh * TT * HS;
    const bf16* Kp = Kb + (size_t)bh * TT * HS;
    const bf16* Vp = Vt + (size_t)bh * HS * TT;

    // Q B-fragments: B[n=q=lane31][k=d in 16m+8h+j]
    v8bf qf[4];
    for (int m = 0; m < 4; m++)
        qf[m] = *(const v8bf*)(Qp + (q0 + lane31) * HS + m * 16 + h * 8);

    v16f o0 = {}, o1 = {};                 // O^T rows d=0..31 / 32..63, col q=lane31
    float m_i = -3.0e38f, l_i = 0.f;       // per-lane (per-q) softmax state

    // staging source addresses (XOR-swizzled chunk so LDS reads spread banks)
    const int kr = tid >> 3, kc = tid & 7;                     // Ks: row kv, 8 chunks of 8
    const bf16* kg = Kp + kr * HS + ((kc ^ (kr & 7)) * 8);
    const int vd = tid >> 2, vc = tid & 3;                     // Vs: row d, 4 chunks of 8
    const bf16* vg = Vp + (size_t)vd * TT + ((vc ^ (vd & 3)) * 8);
    bf16* ksDst = &Ks[wave * 512];  // wave-uniform; HW adds lane*16B
    bf16* vsDst = &Vs[wave * 512];

    const float SC = 0.125f;  // 1/sqrt(64)
    const int kv_max = qb * 128 + 96;
    for (int kv0 = 0; kv0 <= kv_max; kv0 += 32) {
        __syncthreads();
        GLD16(kg + kv0 * HS, ksDst);
        GLD16(vg + kv0, vsDst);
        __syncthreads();
        if (kv0 > q0) continue;  // barriers are at loop top: uniform barrier count
        const bool diag = (kv0 == q0);

        // ---- S^T = K · Q^T ----
        v16f s = {};
        for (int m = 0; m < 4; m++) {
            v8bf af = *(const v8bf*)(&Ks[lane31 * 64 + (((m << 1) | h) ^ (lane31 & 7)) * 8]);
            s = __builtin_amdgcn_mfma_f32_32x32x16_bf16(af, qf[m], s, 0, 0, 0);
        }

        // ---- softmax over kv (16 regs in-lane + partner lane via xor32) ----
        float p[16];
        for (int r = 0; r < 16; r++) {
            float v = s[r] * SC;
            if (diag) {
                int kvr = (r & 3) + 8 * (r >> 2) + 4 * h;  // local kv of this reg
                v = (kvr <= lane31) ? v : -3.0e38f;
            }
            p[r] = v;
        }
        float t8[8];
        for (int r = 0; r < 8; r++) t8[r] = fmaxf(p[r], p[r + 8]);
        float t4a = fmaxf(fmaxf(t8[0], t8[1]), fmaxf(t8[2], t8[3]));
        float t4b = fmaxf(fmaxf(t8[4], t8[5]), fmaxf(t8[6], t8[7]));
        float mx = fmaxf(t4a, t4b);
        mx = fmaxf(mx, __shfl_xor(mx, 32));
        float mn = fmaxf(m_i, mx);
        float alpha = __expf(m_i - mn);
        m_i = mn;
        for (int r = 0; r < 16; r++) p[r] = __expf(p[r] - mn);
        float a8[8];
        for (int r = 0; r < 8; r++) a8[r] = p[r] + p[r + 8];
        float s4a = (a8[0] + a8[1]) + (a8[2] + a8[3]);
        float s4b = (a8[4] + a8[5]) + (a8[6] + a8[7]);
        float rs = s4a + s4b;
        rs += __shfl_xor(rs, 32);
        l_i = l_i * alpha + rs;
        for (int r = 0; r < 16; r++) { o0[r] *= alpha; o1[r] *= alpha; }

        // ---- pack P to bf16 chunks: chunk g holds kv = 8g+4h+(0..3) ----
        union { v4bf v; unsigned long long u; } ch[4];
        for (int g = 0; g < 4; g++)
            for (int rr = 0; rr < 4; rr++)
                ch[g].v[rr] = (bf16)p[g * 4 + rr];

        // ---- O^T += V^T · P^T  (2 k-halves x 2 d-halves) ----
        for (int t = 0; t < 2; t++) {
            // B-frag needs kv 16t+8h+0..7: j0..3 from h'=0 lane's chunk(2t+h), j4..7 from h'=1 lane's
            unsigned long long mine0 = ch[2 * t].u, mine1 = ch[2 * t + 1].u;
            unsigned long long send = h ? mine0 : mine1;
            unsigned long long recv = __shfl_xor(send, 32);
            union { v8bf v; unsigned long long u[2]; } bfr;
            bfr.u[0] = h ? recv : mine0;
            bfr.u[1] = h ? mine1 : recv;
            int cidx = (((t << 1) | h) ^ (lane31 & 3)) * 8;
            v8bf va0 = *(const v8bf*)(&Vs[lane31 * 32 + cidx]);
            o0 = __builtin_amdgcn_mfma_f32_32x32x16_bf16(va0, bfr.v, o0, 0, 0, 0);
            v8bf va1 = *(const v8bf*)(&Vs[(32 + lane31) * 32 + cidx]);
            o1 = __builtin_amdgcn_mfma_f32_32x32x16_bf16(va1, bfr.v, o1, 0, 0, 0);
        }
    }

    // ---- epilogue: O^T/l -> Ob[b][t][hh*64+d], 8B packed stores (4 consecutive d per chunk) ----
    const int b = bh >> 4, hh = bh & 15;
    const int q = q0 + lane31;
    float invl = 1.f / l_i;
    bf16* outRow = Ob + ((size_t)(b * TT + q)) * CE + hh * HS;
    for (int g = 0; g < 4; g++) {
        v4bf w0, w1;
        for (int rr = 0; rr < 4; rr++) {
            w0[rr] = (bf16)(o0[g * 4 + rr] * invl);
            w1[rr] = (bf16)(o1[g * 4 + rr] * invl);
        }
        *(v4bf*)(outRow + g * 8 + h * 4) = w0;
        *(v4bf*)(outRow + 32 + g * 8 + h * 4) = w1;
    }
}

extern "C" void kernel_launch(void* const* d_in, const int* in_sizes, int n_in,
                              void* d_out, int out_size, void* d_ws, size_t ws_size,
                              hipStream_t stream) {
    const float* x  = (const float*)d_in[0];
    const float* Wq = (const float*)d_in[1];
    const float* Wk = (const float*)d_in[2];
    const float* Wv = (const float*)d_in[3];
    const float* Wp = (const float*)d_in[4];
    const float* bp = (const float*)d_in[5];
    char* ws = (char*)d_ws;
    const size_t MB = 1024 * 1024;
    bf16* Xb  = (bf16*)(ws);
    bf16* WqT = (bf16*)(ws + 16 * MB);
    bf16* WkT = (bf16*)(ws + 18 * MB);
    bf16* WvT = (bf16*)(ws + 20 * MB);
    bf16* WpT = (bf16*)(ws + 22 * MB);
    bf16* Qb  = (bf16*)(ws + 24 * MB);
    bf16* Kb  = (bf16*)(ws + 40 * MB);
    bf16* Vt  = (bf16*)(ws + 56 * MB);
    bf16* Ob  = (bf16*)(ws + 72 * MB);

    cast_x_kernel<<<dim3(4096), dim3(256), 0, stream>>>(x, Xb);
    transpose_w_kernel<<<dim3(16, 16), dim3(256), 0, stream>>>(Wq, WqT);
    transpose_w_kernel<<<dim3(16, 16), dim3(256), 0, stream>>>(Wk, WkT);
    transpose_w_kernel<<<dim3(16, 16), dim3(256), 0, stream>>>(Wv, WvT);
    transpose_w_kernel<<<dim3(16, 16), dim3(256), 0, stream>>>(Wp, WpT);

    dim3 gg(8, 64);
    gemm_bt<0><<<gg, dim3(256), 0, stream>>>(Xb, WqT, (void*)Qb, nullptr);
    gemm_bt<0><<<gg, dim3(256), 0, stream>>>(Xb, WkT, (void*)Kb, nullptr);
    gemm_bt<2><<<gg, dim3(256), 0, stream>>>(Xb, WvT, (void*)Vt, nullptr);

    rope_kernel<<<dim3(16384, 2), dim3(256), 0, stream>>>(Qb, Kb);

    attn_kernel<<<dim3(1024), dim3(256), 0, stream>>>(Qb, Kb, Vt, Ob);

    gemm_bt<1><<<gg, dim3(256), 0, stream>>>(Ob, WpT, d_out, bp);
}

// Round 3
// 302.386 us; speedup vs baseline: 2.2805x; 1.0251x over previous
//
#include <hip/hip_runtime.h>
#include <hip/hip_bf16.h>

#define NH 16
#define HS 64
#define CE 1024
#define BB 4
#define TT 2048

typedef __bf16 bf16;
typedef __bf16 v8bf __attribute__((ext_vector_type(8)));
typedef __bf16 v4bf __attribute__((ext_vector_type(4)));
typedef __bf16 v2bf __attribute__((ext_vector_type(2)));
typedef float v4f __attribute__((ext_vector_type(4)));
typedef float v16f __attribute__((ext_vector_type(16)));

#define GLD16(gp, lp)                                                              \
    __builtin_amdgcn_global_load_lds((const __attribute__((address_space(1))) void*)(gp), \
                                     (__attribute__((address_space(3))) void*)(lp), 16, 0, 0)

// ---------------- cast x (fp32 -> bf16), 8 elems/thread ----------------
__global__ __launch_bounds__(256) void cast_x_kernel(const float* __restrict__ x,
                                                     bf16* __restrict__ xb) {
    int idx = (blockIdx.x * 256 + threadIdx.x) * 8;
    const float4* xp = (const float4*)(x + idx);
    float4 a = xp[0], b = xp[1];
    v8bf o;
    o[0] = (bf16)a.x; o[1] = (bf16)a.y; o[2] = (bf16)a.z; o[3] = (bf16)a.w;
    o[4] = (bf16)b.x; o[5] = (bf16)b.y; o[6] = (bf16)b.z; o[7] = (bf16)b.w;
    *(v8bf*)(xb + idx) = o;
}

// ---------------- transpose + cast all 4 weights: W (K x N fp32) -> Wt (N x K bf16) --------
// z = 0..2 -> WqkvT rows z*1024.., z = 3 -> WpT
__global__ __launch_bounds__(256) void transpose_w_kernel(const float* __restrict__ W0,
                                                          const float* __restrict__ W1,
                                                          const float* __restrict__ W2,
                                                          const float* __restrict__ W3,
                                                          bf16* __restrict__ dqkv,
                                                          bf16* __restrict__ dp) {
    __shared__ bf16 tile[64][66];
    int z = blockIdx.z;
    const float* W = (z == 0) ? W0 : (z == 1) ? W1 : (z == 2) ? W2 : W3;
    bf16* Wt = (z < 3) ? (dqkv + (size_t)z * 1024 * CE) : dp;
    int k0 = blockIdx.x * 64;
    int n0 = blockIdx.y * 64;
    int tx = threadIdx.x & 63;
    int ty = threadIdx.x >> 6;  // 0..3
    for (int s = 0; s < 16; s++) {
        int r = s * 4 + ty;
        tile[r][tx] = (bf16)W[(size_t)(k0 + r) * CE + n0 + tx];
    }
    __syncthreads();
    for (int s = 0; s < 16; s++) {
        int r = s * 4 + ty;
        Wt[(size_t)(n0 + r) * CE + k0 + tx] = tile[tx][r];
    }
}

// ---------------- GEMM, BK=64: C(8192 x N) = A(8192x1024) * Bt(N x 1024)^T ----------------
// MODE 0: fused QKV (N=3072). n<1024 -> Qb [B][H][T][64]; <2048 -> Kb same; else Vt [B][H][64][T]
// MODE 1: final projection (N=1024), fp32 out + bias
template <int MODE>
__global__ __launch_bounds__(256) void gemm_bt(const bf16* __restrict__ A,
                                               const bf16* __restrict__ Bt,
                                               bf16* __restrict__ Qb_, bf16* __restrict__ Kb_,
                                               bf16* __restrict__ Vt_,
                                               float* __restrict__ Pout,
                                               const float* __restrict__ bias) {
    __shared__ __align__(16) bf16 As[128 * 64];
    __shared__ __align__(16) bf16 Bs[128 * 64];
    const int tid = threadIdx.x;
    const int lane = tid & 63, wave = tid >> 6;
    const int lane15 = lane & 15, quad = lane >> 4;
    const int wr = wave >> 1, wc = wave & 1;
    const int m0 = blockIdx.y * 128;
    const int n0 = blockIdx.x * 128;

    v4f acc[4][4] = {};

    const int cm = tid >> 3;          // 0..31
    const int ck = (tid & 7) * 8;     // 0..56
    const bf16* Ag = A + (size_t)(m0 + cm) * CE + ck;
    const bf16* Bg = Bt + (size_t)(n0 + cm) * CE + ck;
    // dest elem offset for pass p = p*2048 + tid*8; HW adds lane*16B to wave-uniform base
    bf16* aD = &As[wave * 512];
    bf16* bD = &Bs[wave * 512];

    for (int k0 = 0; k0 < CE; k0 += 64) {
        __syncthreads();  // previous iteration's readers done
#pragma unroll
        for (int p = 0; p < 4; p++) GLD16(Ag + k0 + (size_t)(p * 32) * CE, aD + p * 2048);
#pragma unroll
        for (int p = 0; p < 4; p++) GLD16(Bg + k0 + (size_t)(p * 32) * CE, bD + p * 2048);
        __syncthreads();  // vmcnt(0) drain + barrier
#pragma unroll
        for (int kh = 0; kh < 2; kh++) {
            v8bf af[4], bfr[4];
            for (int i = 0; i < 4; i++)
                af[i] = *(const v8bf*)(&As[(wr * 64 + i * 16 + lane15) * 64 + kh * 32 + quad * 8]);
            for (int j = 0; j < 4; j++)
                bfr[j] = *(const v8bf*)(&Bs[(wc * 64 + j * 16 + lane15) * 64 + kh * 32 + quad * 8]);
            for (int i = 0; i < 4; i++)
                for (int j = 0; j < 4; j++)
                    acc[i][j] = __builtin_amdgcn_mfma_f32_16x16x32_bf16(af[i], bfr[j], acc[i][j], 0, 0, 0);
        }
    }

    for (int i = 0; i < 4; i++) {
        for (int j = 0; j < 4; j++) {
            int gmb = m0 + wr * 64 + i * 16 + quad * 4;
            int gn = n0 + wc * 64 + j * 16 + lane15;
            if (MODE == 1) {
                float bb = bias[gn];
                for (int r = 0; r < 4; r++)
                    Pout[(size_t)(gmb + r) * CE + gn] = acc[i][j][r] + bb;
            } else {
                int w = gn >> 10;           // 0=Q 1=K 2=V (block-uniform)
                int n = gn & 1023;
                int h = n >> 6, d = n & 63;
                if (w < 2) {
                    bf16* out = w ? Kb_ : Qb_;
                    for (int r = 0; r < 4; r++) {
                        int gm = gmb + r;
                        int b = gm >> 11, t = gm & 2047;
                        out[(((size_t)(b * NH + h)) * TT + t) * HS + d] = (bf16)acc[i][j][r];
                    }
                } else {  // V transposed: Vt [B][H][HS][T]
                    int b = gmb >> 11, t = gmb & 2047;
                    v4bf pack;
                    for (int r = 0; r < 4; r++) pack[r] = (bf16)acc[i][j][r];
                    *(v4bf*)(&Vt_[(((size_t)(b * NH + h)) * HS + d) * TT + t]) = pack;
                }
            }
        }
    }
}

// ---------------- RoPE in-place on Q/K; Q additionally scaled by 1/sqrt(64) ----------------
__global__ __launch_bounds__(256) void rope_kernel(bf16* __restrict__ Qb, bf16* __restrict__ Kb) {
    unsigned idx = blockIdx.x * 256 + threadIdx.x;  // 0 .. 4M-1 (pairs)
    bool isK = blockIdx.y != 0;
    bf16* buf = isK ? Kb : Qb;
    int i = idx & 31;
    int t = (idx >> 5) & 2047;
    float inv = exp2f(-0.41524101186092034f * (float)i);  // 10000^(-i/32)
    float ang = (float)t * inv;
    float s, c;
    sincosf(ang, &s, &c);
    if (!isK) { s *= 0.125f; c *= 0.125f; }  // fold softmax scale into Q (exact pow2)
    bf16* p = buf + (size_t)idx * 2;
    v2bf v = *(v2bf*)p;
    float x0 = (float)v[0], x1 = (float)v[1];
    v2bf o;
    o[0] = (bf16)(x0 * c - x1 * s);
    o[1] = (bf16)(x0 * s + x1 * c);
    *(v2bf*)p = o;
}

// ---------------- flash attention v3: dual q-tile per wave (causal balancing) ----------------
// Block = 4 waves; block handles q-tiles {p, 15-p} of one (b,h) -> constant work per block.
// Per wave: 32 q rows of tile A (=p) and 32 of tile B (=15-p). S^T = K·Q^T (mfma 32x32x16),
// per-lane softmax state; K/V fragments loaded from LDS ONCE per step, shared by both tiles.
__global__ __launch_bounds__(256, 2) void attn_kernel(const bf16* __restrict__ Qb,
                                                      const bf16* __restrict__ Kb,
                                                      const bf16* __restrict__ Vt,
                                                      bf16* __restrict__ Ob) {
    __shared__ __align__(16) bf16 Ks[32 * 64];  // [kv][d], chunk-swizzled
    __shared__ __align__(16) bf16 Vs[64 * 32];  // [d][kv], chunk-swizzled
    const int tid = threadIdx.x, lane = tid & 63, wave = tid >> 6;
    const int lane31 = lane & 31, h = lane >> 5;
    const int pair = blockIdx.x >> 6;  // 0..7
    const int bh = blockIdx.x & 63;
    const int q0A = pair * 128 + wave * 32;
    const int q0B = (15 - pair) * 128 + wave * 32;
    const bf16* Qp = Qb + (size_t)bh * TT * HS;
    const bf16* Kp = Kb + (size_t)bh * TT * HS;
    const bf16* Vp = Vt + (size_t)bh * HS * TT;

    v8bf qfA[4], qfB[4];
    for (int m = 0; m < 4; m++) {
        qfA[m] = *(const v8bf*)(Qp + (q0A + lane31) * HS + m * 16 + h * 8);
        qfB[m] = *(const v8bf*)(Qp + (q0B + lane31) * HS + m * 16 + h * 8);
    }

    v16f oA0 = {}, oA1 = {}, oB0 = {}, oB1 = {};
    float mA = -3.0e38f, lA = 0.f, mB = -3.0e38f, lB = 0.f;

    const int kr = tid >> 3, kc = tid & 7;
    const bf16* kg = Kp + kr * HS + ((kc ^ (kr & 7)) * 8);
    const int vd = tid >> 2, vc = tid & 3;
    const bf16* vg = Vp + (size_t)vd * TT + ((vc ^ (vd & 3)) * 8);
    bf16* ksDst = &Ks[wave * 512];
    bf16* vsDst = &Vs[wave * 512];

    v8bf kf[4], vf[2][2];

    auto step = [&](const v8bf* qf, v16f& o0, v16f& o1, float& m_i, float& l_i, bool diag) {
        v16f s = {};
        for (int m = 0; m < 4; m++)
            s = __builtin_amdgcn_mfma_f32_32x32x16_bf16(kf[m], qf[m], s, 0, 0, 0);
        float p[16];
        for (int r = 0; r < 16; r++) {
            float v = s[r];
            if (diag) {
                int kvr = (r & 3) + 8 * (r >> 2) + 4 * h;
                v = (kvr <= lane31) ? v : -3.0e38f;
            }
            p[r] = v;
        }
        float t8[8];
        for (int r = 0; r < 8; r++) t8[r] = fmaxf(p[r], p[r + 8]);
        float mx = fmaxf(fmaxf(fmaxf(t8[0], t8[1]), fmaxf(t8[2], t8[3])),
                         fmaxf(fmaxf(t8[4], t8[5]), fmaxf(t8[6], t8[7])));
        mx = fmaxf(mx, __shfl_xor(mx, 32));
        bool anyUpd = __ballot(mx > m_i) != 0ull;
        float mn = fmaxf(m_i, mx);
        for (int r = 0; r < 16; r++) p[r] = __expf(p[r] - mn);
        float a8[8];
        for (int r = 0; r < 8; r++) a8[r] = p[r] + p[r + 8];
        float rs = ((a8[0] + a8[1]) + (a8[2] + a8[3])) + ((a8[4] + a8[5]) + (a8[6] + a8[7]));
        rs += __shfl_xor(rs, 32);
        if (anyUpd) {
            float alpha = __expf(m_i - mn);
            m_i = mn;
            l_i = l_i * alpha + rs;
            for (int r = 0; r < 16; r++) { o0[r] *= alpha; o1[r] *= alpha; }
        } else {
            l_i += rs;
        }
        union { v4bf v; unsigned long long u; } ch[4];
        for (int g = 0; g < 4; g++)
            for (int rr = 0; rr < 4; rr++)
                ch[g].v[rr] = (bf16)p[g * 4 + rr];
        for (int t = 0; t < 2; t++) {
            unsigned long long mine0 = ch[2 * t].u, mine1 = ch[2 * t + 1].u;
            unsigned long long send = h ? mine0 : mine1;
            unsigned long long recv = __shfl_xor(send, 32);
            union { v8bf v; unsigned long long u[2]; } bfr;
            bfr.u[0] = h ? recv : mine0;
            bfr.u[1] = h ? mine1 : recv;
            o0 = __builtin_amdgcn_mfma_f32_32x32x16_bf16(vf[t][0], bfr.v, o0, 0, 0, 0);
            o1 = __builtin_amdgcn_mfma_f32_32x32x16_bf16(vf[t][1], bfr.v, o1, 0, 0, 0);
        }
    };

    const int kv_end = (15 - pair) * 128 + 96;
    for (int kv0 = 0; kv0 <= kv_end; kv0 += 32) {
        __syncthreads();
        GLD16(kg + kv0 * HS, ksDst);
        GLD16(vg + kv0, vsDst);
        __syncthreads();
        for (int m = 0; m < 4; m++)
            kf[m] = *(const v8bf*)(&Ks[lane31 * 64 + (((m << 1) | h) ^ (lane31 & 7)) * 8]);
        for (int t = 0; t < 2; t++)
            for (int dh = 0; dh < 2; dh++)
                vf[t][dh] = *(const v8bf*)(&Vs[(dh * 32 + lane31) * 32 + ((((t << 1) | h) ^ (lane31 & 3)) * 8)]);
        if (kv0 <= q0B) step(qfB, oB0, oB1, mB, lB, kv0 == q0B);
        if (kv0 <= q0A) step(qfA, oA0, oA1, mA, lA, kv0 == q0A);
    }

    const int b = bh >> 4, hh = bh & 15;
    auto writeO = [&](int q0, v16f& o0, v16f& o1, float l_i) {
        int q = q0 + lane31;
        float invl = 1.f / l_i;
        bf16* outRow = Ob + ((size_t)(b * TT + q)) * CE + hh * HS;
        for (int g = 0; g < 4; g++) {
            v4bf w0, w1;
            for (int rr = 0; rr < 4; rr++) {
                w0[rr] = (bf16)(o0[g * 4 + rr] * invl);
                w1[rr] = (bf16)(o1[g * 4 + rr] * invl);
            }
            *(v4bf*)(outRow + g * 8 + h * 4) = w0;
            *(v4bf*)(outRow + 32 + g * 8 + h * 4) = w1;
        }
    };
    writeO(q0A, oA0, oA1, lA);
    writeO(q0B, oB0, oB1, lB);
}

extern "C" void kernel_launch(void* const* d_in, const int* in_sizes, int n_in,
                              void* d_out, int out_size, void* d_ws, size_t ws_size,
                              hipStream_t stream) {
    const float* x  = (const float*)d_in[0];
    const float* Wq = (const float*)d_in[1];
    const float* Wk = (const float*)d_in[2];
    const float* Wv = (const float*)d_in[3];
    const float* Wp = (const float*)d_in[4];
    const float* bp = (const float*)d_in[5];
    char* ws = (char*)d_ws;
    const size_t MB = 1024 * 1024;
    bf16* Xb    = (bf16*)(ws);
    bf16* WqkvT = (bf16*)(ws + 16 * MB);  // 3072 x 1024 (Q,K,V stacked)
    bf16* WpT   = (bf16*)(ws + 22 * MB);
    bf16* Qb    = (bf16*)(ws + 24 * MB);
    bf16* Kb    = (bf16*)(ws + 40 * MB);
    bf16* Vt    = (bf16*)(ws + 56 * MB);
    bf16* Ob    = (bf16*)(ws + 72 * MB);

    cast_x_kernel<<<dim3(4096), dim3(256), 0, stream>>>(x, Xb);
    transpose_w_kernel<<<dim3(16, 16, 4), dim3(256), 0, stream>>>(Wq, Wk, Wv, Wp, WqkvT, WpT);

    gemm_bt<0><<<dim3(24, 64), dim3(256), 0, stream>>>(Xb, WqkvT, Qb, Kb, Vt, nullptr, nullptr);

    rope_kernel<<<dim3(16384, 2), dim3(256), 0, stream>>>(Qb, Kb);

    attn_kernel<<<dim3(512), dim3(256), 0, stream>>>(Qb, Kb, Vt, Ob);

    gemm_bt<1><<<dim3(8, 64), dim3(256), 0, stream>>>(Ob, WpT, nullptr, nullptr, nullptr,
                                                      (float*)d_out, bp);
}

// Round 4
// 276.885 us; speedup vs baseline: 2.4906x; 1.0921x over previous
//
#include <hip/hip_runtime.h>
#include <hip/hip_bf16.h>

#define NH 16
#define HS 64
#define CE 1024
#define BB 4
#define TT 2048

typedef __bf16 bf16;
typedef __bf16 v8bf __attribute__((ext_vector_type(8)));
typedef __bf16 v4bf __attribute__((ext_vector_type(4)));
typedef __bf16 v2bf __attribute__((ext_vector_type(2)));
typedef float v4f __attribute__((ext_vector_type(4)));
typedef float v16f __attribute__((ext_vector_type(16)));

#define GLD16(gp, lp)                                                              \
    __builtin_amdgcn_global_load_lds((const __attribute__((address_space(1))) void*)(gp), \
                                     (__attribute__((address_space(3))) void*)(lp), 16, 0, 0)

#if __has_builtin(__builtin_amdgcn_exp2f)
#define EXP2(x) __builtin_amdgcn_exp2f(x)
#else
#define EXP2(x) exp2f(x)
#endif

// ---------------- cast x (fp32 -> bf16), 8 elems/thread ----------------
__global__ __launch_bounds__(256) void cast_x_kernel(const float* __restrict__ x,
                                                     bf16* __restrict__ xb) {
    int idx = (blockIdx.x * 256 + threadIdx.x) * 8;
    const float4* xp = (const float4*)(x + idx);
    float4 a = xp[0], b = xp[1];
    v8bf o;
    o[0] = (bf16)a.x; o[1] = (bf16)a.y; o[2] = (bf16)a.z; o[3] = (bf16)a.w;
    o[4] = (bf16)b.x; o[5] = (bf16)b.y; o[6] = (bf16)b.z; o[7] = (bf16)b.w;
    *(v8bf*)(xb + idx) = o;
}

// ---------------- transpose + cast all 4 weights: W (K x N fp32) -> Wt (N x K bf16) --------
__global__ __launch_bounds__(256) void transpose_w_kernel(const float* __restrict__ W0,
                                                          const float* __restrict__ W1,
                                                          const float* __restrict__ W2,
                                                          const float* __restrict__ W3,
                                                          bf16* __restrict__ dqkv,
                                                          bf16* __restrict__ dp) {
    __shared__ bf16 tile[64][66];
    int z = blockIdx.z;
    const float* W = (z == 0) ? W0 : (z == 1) ? W1 : (z == 2) ? W2 : W3;
    bf16* Wt = (z < 3) ? (dqkv + (size_t)z * 1024 * CE) : dp;
    int k0 = blockIdx.x * 64;
    int n0 = blockIdx.y * 64;
    int tx = threadIdx.x & 63;
    int ty = threadIdx.x >> 6;  // 0..3
    for (int s = 0; s < 16; s++) {
        int r = s * 4 + ty;
        tile[r][tx] = (bf16)W[(size_t)(k0 + r) * CE + n0 + tx];
    }
    __syncthreads();
    for (int s = 0; s < 16; s++) {
        int r = s * 4 + ty;
        Wt[(size_t)(n0 + r) * CE + k0 + tx] = tile[tx][r];
    }
}

// ---------------- GEMM, BK=64, XOR-swizzled LDS: C(8192 x N) = A * Bt^T ----------------
// LDS layout: elem (row, k) at row*64 + ((k>>3)^(row&7))*8 + (k&7)  -> conflict-free b128 reads
// MODE 0: fused QKV (N=3072). n<1024 -> Qb; <2048 -> Kb; else Vt [B][H][64][T]
// MODE 1: final projection (N=1024), fp32 out + bias
template <int MODE>
__global__ __launch_bounds__(256) void gemm_bt(const bf16* __restrict__ A,
                                               const bf16* __restrict__ Bt,
                                               bf16* __restrict__ Qb_, bf16* __restrict__ Kb_,
                                               bf16* __restrict__ Vt_,
                                               float* __restrict__ Pout,
                                               const float* __restrict__ bias) {
    __shared__ __align__(16) bf16 As[128 * 64];
    __shared__ __align__(16) bf16 Bs[128 * 64];
    const int tid = threadIdx.x;
    const int lane = tid & 63, wave = tid >> 6;
    const int lane15 = lane & 15, quad = lane >> 4;
    const int wr = wave >> 1, wc = wave & 1;
    const int m0 = blockIdx.y * 128;
    const int n0 = blockIdx.x * 128;

    v4f acc[4][4] = {};

    const int cm = tid >> 3;                              // 0..31 (row within 32-row pass)
    const int ck = ((tid & 7) ^ (cm & 7)) * 8;            // swizzled source k-chunk
    const bf16* Ag = A + (size_t)(m0 + cm) * CE + ck;
    const bf16* Bg = Bt + (size_t)(n0 + cm) * CE + ck;
    bf16* aD = &As[wave * 512];
    bf16* bD = &Bs[wave * 512];

    for (int k0 = 0; k0 < CE; k0 += 64) {
        __syncthreads();  // previous iteration's readers done
#pragma unroll
        for (int p = 0; p < 4; p++) GLD16(Ag + k0 + (size_t)(p * 32) * CE, aD + p * 2048);
#pragma unroll
        for (int p = 0; p < 4; p++) GLD16(Bg + k0 + (size_t)(p * 32) * CE, bD + p * 2048);
        __syncthreads();  // vmcnt(0) drain + barrier
#pragma unroll
        for (int kh = 0; kh < 2; kh++) {
            v8bf af[4], bfr[4];
            for (int i = 0; i < 4; i++) {
                int row = wr * 64 + i * 16 + lane15;
                af[i] = *(const v8bf*)(&As[row * 64 + (((kh * 4 + quad) ^ (lane15 & 7)) * 8)]);
            }
            for (int j = 0; j < 4; j++) {
                int row = wc * 64 + j * 16 + lane15;
                bfr[j] = *(const v8bf*)(&Bs[row * 64 + (((kh * 4 + quad) ^ (lane15 & 7)) * 8)]);
            }
            for (int i = 0; i < 4; i++)
                for (int j = 0; j < 4; j++)
                    acc[i][j] = __builtin_amdgcn_mfma_f32_16x16x32_bf16(af[i], bfr[j], acc[i][j], 0, 0, 0);
        }
    }

    for (int i = 0; i < 4; i++) {
        for (int j = 0; j < 4; j++) {
            int gmb = m0 + wr * 64 + i * 16 + quad * 4;
            int gn = n0 + wc * 64 + j * 16 + lane15;
            if (MODE == 1) {
                float bb = bias[gn];
                for (int r = 0; r < 4; r++)
                    Pout[(size_t)(gmb + r) * CE + gn] = acc[i][j][r] + bb;
            } else {
                int w = gn >> 10;           // 0=Q 1=K 2=V (block-uniform)
                int n = gn & 1023;
                int h = n >> 6, d = n & 63;
                if (w < 2) {
                    bf16* out = w ? Kb_ : Qb_;
                    for (int r = 0; r < 4; r++) {
                        int gm = gmb + r;
                        int b = gm >> 11, t = gm & 2047;
                        out[(((size_t)(b * NH + h)) * TT + t) * HS + d] = (bf16)acc[i][j][r];
                    }
                } else {  // V transposed: Vt [B][H][HS][T]
                    int b = gmb >> 11, t = gmb & 2047;
                    v4bf pack;
                    for (int r = 0; r < 4; r++) pack[r] = (bf16)acc[i][j][r];
                    *(v4bf*)(&Vt_[(((size_t)(b * NH + h)) * HS + d) * TT + t]) = pack;
                }
            }
        }
    }
}

// ---------------- RoPE in-place; Q additionally scaled by log2(e)/sqrt(64) ----------------
// (softmax then runs in base-2: exp(x*sc - m) == 2^(x*sc*log2e - m'), fold into Q)
__global__ __launch_bounds__(256) void rope_kernel(bf16* __restrict__ Qb, bf16* __restrict__ Kb) {
    unsigned idx = blockIdx.x * 256 + threadIdx.x;  // 0 .. 4M-1 (pairs)
    bool isK = blockIdx.y != 0;
    bf16* buf = isK ? Kb : Qb;
    int i = idx & 31;
    int t = (idx >> 5) & 2047;
    float inv = exp2f(-0.41524101186092034f * (float)i);  // 10000^(-i/32)
    float ang = (float)t * inv;
    float s, c;
    sincosf(ang, &s, &c);
    if (!isK) {
        const float QS = 0.18033688011112042f;  // 0.125 * log2(e)
        s *= QS; c *= QS;
    }
    bf16* p = buf + (size_t)idx * 2;
    v2bf v = *(v2bf*)p;
    float x0 = (float)v[0], x1 = (float)v[1];
    v2bf o;
    o[0] = (bf16)(x0 * c - x1 * s);
    o[1] = (bf16)(x0 * s + x1 * c);
    *(v2bf*)p = o;
}

// ---------------- flash attention (R2 structure): 1 wave = 32 q rows, S^T layout -----------
// CU-balanced tile remap: round-robin dispatch puts blocks {b, b+256, b+512, b+768} on one CU;
// tile(g,base) = {base, 7-base, 8+base, 15-base} makes each CU's 4 blocks sum to 30 tile-steps.
__global__ __launch_bounds__(256, 4) void attn_kernel(const bf16* __restrict__ Qb,
                                                      const bf16* __restrict__ Kb,
                                                      const bf16* __restrict__ Vt,
                                                      bf16* __restrict__ Ob) {
    __shared__ __align__(16) bf16 Ks[32 * 64];  // [kv][d], chunk-swizzled
    __shared__ __align__(16) bf16 Vs[64 * 32];  // [d][kv], chunk-swizzled
    const int tid = threadIdx.x, lane = tid & 63, wave = tid >> 6;
    const int lane31 = lane & 31, h = lane >> 5;
    const int bh = blockIdx.x & 63;
    const int base = (blockIdx.x >> 6) & 3;
    const int g = blockIdx.x >> 8;  // 0..3
    const int qb = (g == 0) ? base : (g == 1) ? 7 - base : (g == 2) ? 8 + base : 15 - base;
    const int q0 = qb * 128 + wave * 32;
    const bf16* Qp = Qb + (size_t)bh * TT * HS;
    const bf16* Kp = Kb + (size_t)bh * TT * HS;
    const bf16* Vp = Vt + (size_t)bh * HS * TT;

    // Q B-fragments: B[n=q=lane31][k=d in 16m+8h+j]
    v8bf qf[4];
    for (int m = 0; m < 4; m++)
        qf[m] = *(const v8bf*)(Qp + (q0 + lane31) * HS + m * 16 + h * 8);

    v16f o0 = {}, o1 = {};                 // O^T rows d=0..31 / 32..63, col q=lane31
    float m_i = -3.0e38f, l_i = 0.f;       // per-lane (per-q) softmax state (base-2 domain)

    const int kr = tid >> 3, kc = tid & 7;
    const bf16* kg = Kp + kr * HS + ((kc ^ (kr & 7)) * 8);
    const int vd = tid >> 2, vc = tid & 3;
    const bf16* vg = Vp + (size_t)vd * TT + ((vc ^ (vd & 3)) * 8);
    bf16* ksDst = &Ks[wave * 512];
    bf16* vsDst = &Vs[wave * 512];

    const int kv_max = qb * 128 + 96;
    for (int kv0 = 0; kv0 <= kv_max; kv0 += 32) {
        __syncthreads();
        GLD16(kg + kv0 * HS, ksDst);
        GLD16(vg + kv0, vsDst);
        __syncthreads();
        if (kv0 > q0) continue;  // uniform barrier count across waves
        const bool diag = (kv0 == q0);

        // ---- S^T = K · Q^T ----
        v16f s = {};
        for (int m = 0; m < 4; m++) {
            v8bf af = *(const v8bf*)(&Ks[lane31 * 64 + (((m << 1) | h) ^ (lane31 & 7)) * 8]);
            s = __builtin_amdgcn_mfma_f32_32x32x16_bf16(af, qf[m], s, 0, 0, 0);
        }

        // ---- base-2 online softmax (in-reg tree + 1 shfl_xor(32)) ----
        float p[16];
        for (int r = 0; r < 16; r++) {
            float v = s[r];
            if (diag) {
                int kvr = (r & 3) + 8 * (r >> 2) + 4 * h;
                v = (kvr <= lane31) ? v : -3.0e38f;
            }
            p[r] = v;
        }
        float t8[8];
        for (int r = 0; r < 8; r++) t8[r] = fmaxf(p[r], p[r + 8]);
        float mx = fmaxf(fmaxf(fmaxf(t8[0], t8[1]), fmaxf(t8[2], t8[3])),
                         fmaxf(fmaxf(t8[4], t8[5]), fmaxf(t8[6], t8[7])));
        mx = fmaxf(mx, __shfl_xor(mx, 32));
        bool anyUpd = __ballot(mx > m_i) != 0ull;
        float mn = fmaxf(m_i, mx);
        for (int r = 0; r < 16; r++) p[r] = EXP2(p[r] - mn);
        float a8[8];
        for (int r = 0; r < 8; r++) a8[r] = p[r] + p[r + 8];
        float rs = ((a8[0] + a8[1]) + (a8[2] + a8[3])) + ((a8[4] + a8[5]) + (a8[6] + a8[7]));
        rs += __shfl_xor(rs, 32);
        if (anyUpd) {
            float alpha = EXP2(m_i - mn);
            m_i = mn;
            l_i = l_i * alpha + rs;
            for (int r = 0; r < 16; r++) { o0[r] *= alpha; o1[r] *= alpha; }
        } else {
            l_i += rs;
        }

        // ---- pack P; chunk g holds kv = 8g+4h+(0..3) ----
        union { v4bf v; unsigned long long u; } ch[4];
        for (int gg = 0; gg < 4; gg++)
            for (int rr = 0; rr < 4; rr++)
                ch[gg].v[rr] = (bf16)p[gg * 4 + rr];

        // ---- O^T += V^T · P^T ----
        for (int t = 0; t < 2; t++) {
            unsigned long long mine0 = ch[2 * t].u, mine1 = ch[2 * t + 1].u;
            unsigned long long send = h ? mine0 : mine1;
            unsigned long long recv = __shfl_xor(send, 32);
            union { v8bf v; unsigned long long u[2]; } bfr;
            bfr.u[0] = h ? recv : mine0;
            bfr.u[1] = h ? mine1 : recv;
            int cidx = (((t << 1) | h) ^ (lane31 & 3)) * 8;
            v8bf va0 = *(const v8bf*)(&Vs[lane31 * 32 + cidx]);
            o0 = __builtin_amdgcn_mfma_f32_32x32x16_bf16(va0, bfr.v, o0, 0, 0, 0);
            v8bf va1 = *(const v8bf*)(&Vs[(32 + lane31) * 32 + cidx]);
            o1 = __builtin_amdgcn_mfma_f32_32x32x16_bf16(va1, bfr.v, o1, 0, 0, 0);
        }
    }

    const int b = bh >> 4, hh = bh & 15;
    const int q = q0 + lane31;
    float invl = 1.f / l_i;
    bf16* outRow = Ob + ((size_t)(b * TT + q)) * CE + hh * HS;
    for (int gg = 0; gg < 4; gg++) {
        v4bf w0, w1;
        for (int rr = 0; rr < 4; rr++) {
            w0[rr] = (bf16)(o0[gg * 4 + rr] * invl);
            w1[rr] = (bf16)(o1[gg * 4 + rr] * invl);
        }
        *(v4bf*)(outRow + gg * 8 + h * 4) = w0;
        *(v4bf*)(outRow + 32 + gg * 8 + h * 4) = w1;
    }
}

extern "C" void kernel_launch(void* const* d_in, const int* in_sizes, int n_in,
                              void* d_out, int out_size, void* d_ws, size_t ws_size,
                              hipStream_t stream) {
    const float* x  = (const float*)d_in[0];
    const float* Wq = (const float*)d_in[1];
    const float* Wk = (const float*)d_in[2];
    const float* Wv = (const float*)d_in[3];
    const float* Wp = (const float*)d_in[4];
    const float* bp = (const float*)d_in[5];
    char* ws = (char*)d_ws;
    const size_t MB = 1024 * 1024;
    bf16* Xb    = (bf16*)(ws);
    bf16* WqkvT = (bf16*)(ws + 16 * MB);  // 3072 x 1024 (Q,K,V stacked)
    bf16* WpT   = (bf16*)(ws + 22 * MB);
    bf16* Qb    = (bf16*)(ws + 24 * MB);
    bf16* Kb    = (bf16*)(ws + 40 * MB);
    bf16* Vt    = (bf16*)(ws + 56 * MB);
    bf16* Ob    = (bf16*)(ws + 72 * MB);

    cast_x_kernel<<<dim3(4096), dim3(256), 0, stream>>>(x, Xb);
    transpose_w_kernel<<<dim3(16, 16, 4), dim3(256), 0, stream>>>(Wq, Wk, Wv, Wp, WqkvT, WpT);

    gemm_bt<0><<<dim3(24, 64), dim3(256), 0, stream>>>(Xb, WqkvT, Qb, Kb, Vt, nullptr, nullptr);

    rope_kernel<<<dim3(16384, 2), dim3(256), 0, stream>>>(Qb, Kb);

    attn_kernel<<<dim3(1024), dim3(256), 0, stream>>>(Qb, Kb, Vt, Ob);

    gemm_bt<1><<<dim3(8, 64), dim3(256), 0, stream>>>(Ob, WpT, nullptr, nullptr, nullptr,
                                                      (float*)d_out, bp);
}